// Round 13
// baseline (113.278 us; speedup 1.0000x reference)
//
#include <hip/hip_runtime.h>
#include <math.h>

#define NN 16384
#define T 236
#define TILES 70   // ceil(16384/236); wrap-tile duplicate outputs are bitwise-identical

typedef float f2 __attribute__((ext_vector_type(2)));

// Genuine packed fp32 FMA (gfx950 VOP3P). acc += x * {w,w}.
// All call sites have naturally even-aligned VGPR-pair sources (batch-packed),
// so no mov overhead; w is uniform -> SGPR pair.
__device__ __forceinline__ void pkfma(f2& acc, f2 x, float w) {
    f2 ws = {w, w};
    asm("v_pk_fma_f32 %0, %1, %2, %0" : "+v"(acc) : "v"(x), "s"(ws));
}

__device__ __forceinline__ f2 elu2(f2 v) {
    f2 r;
    r.x = fmaxf(v.x, 0.0f) + fminf(__expf(v.x) - 1.0f, 0.0f);
    r.y = fmaxf(v.y, 0.0f) + fminf(__expf(v.y) - 1.0f, 0.0f);
    return r;
}

// ---- setup: composite 9-tap weights cw[6][9] = conv1 ∘ [deriv ; I - box] ----
__global__ void smag_setup(const float* __restrict__ dw,
                           const float* __restrict__ fw,
                           const float* __restrict__ W1,
                           float* __restrict__ cw)
{
    const int t = threadIdx.x;
    if (t < 54) {
        const int c = t / 9;
        const int m = (t % 9) - 4;
        float acc = 0.0f;
        #pragma unroll
        for (int k = 0; k < 5; ++k) {
            int j = m + 4 - k;
            if (j >= 0 && j <= 4) acc += W1[c * 10 + k] * dw[j];
        }
        if (m >= -2 && m <= 2) acc += W1[c * 10 + 5 + (m + 2)];
        #pragma unroll
        for (int i = 0; i < 3; ++i) {
            int k = m + 3 - i;
            if (k >= 0 && k <= 4) acc -= fw[i] * W1[c * 10 + 5 + k];
        }
        cw[t] = acc;
    }
}

__global__ __launch_bounds__(256, 8)
void smag_bp(const float* __restrict__ x,
             const float* __restrict__ dw,
             const float* __restrict__ cw,    // [6][9] composite
             const float* __restrict__ b1,
             const float* __restrict__ W2, const float* __restrict__ b2,
             const float* __restrict__ W3, const float* __restrict__ b3,
             float* __restrict__ out)
{
    const int tile = (int)(blockIdx.x % TILES);
    const int rp   = (int)(blockIdx.x / TILES);   // row pair
    const int tb   = tile * T;
    const int tid  = threadIdx.x;
    const float* __restrict__ x0 = x + (size_t)(2 * rp) * NN;
    const float* __restrict__ x1 = x0 + NN;
    float* __restrict__ o0 = out + (size_t)(2 * rp) * NN;
    float* __restrict__ o1 = o0 + NN;

    // Interleaved arena: every f2 = {row0, row1} -> all LDS accesses aligned b64
    // (lane stride 8B = 2-way bank aliasing = free).
    //   sxi [0,512)      x   : (pos+10)*2 + r, pos in [-10,T+10)   live stage..S4
    //   sh1 [512,3488)   h1  : c*496 + (pos+6)*2 + r, pos in [-6,T+6)  live S2..S3
    //   sh2 [3488,4952)  h2  : c*488 + (pos+4)*2 + r, pos in [-4,T+4)  live S3..S4
    //   sy  [512,992)    y   : (pos+2)*2 + r, pos in [-2,T+2)   aliases sh1 (dead)
    __shared__ __align__(16) float sm[4952];
    float* const sxi = sm;
    float* const sh1 = sm + 512;
    float* const sh2 = sm + 3488;
    float* const sy  = sm + 512;

    // ---- stage x interleaved (2 coalesced row streams, b64 write) ----
    {
        const int pos = tid - 10;                    // [-10, T+10) : exactly 256
        const int g = (tb + pos + NN) & (NN - 1);
        f2 v = {x0[g], x1[g]};
        *(f2*)(sxi + 2 * tid) = v;
    }
    __syncthreads();

    // ---- S2': h1 = elu(conv9(x,cw)+b1), pos q in [-6,T+6), 248 threads ----
    if (tid < T + 12) {
        const int q = tid - 6;
        const float* xb = sxi + (q + 6) * 2;         // pos q-4 -> (q-4+10)*2
        f2 X[9];
        #pragma unroll
        for (int m = 0; m < 9; ++m) X[m] = *(const f2*)(xb + 2 * m);
        #pragma unroll
        for (int c = 0; c < 6; ++c) {
            f2 a = {b1[c], b1[c]};
            #pragma unroll
            for (int m = 0; m < 9; ++m) pkfma(a, X[m], cw[c * 9 + m]);
            *(f2*)(sh1 + c * 496 + (q + 6) * 2) = elu2(a);
        }
    }
    __syncthreads();

    // ---- S3: h2 = elu(conv5(h1,W2)+b2), pos u in [-4,T+4), 244 threads ----
    if (tid < T + 8) {
        const int u = tid - 4;
        f2 a0 = {b2[0], b2[0]};
        f2 a1 = {b2[1], b2[1]};
        f2 a2 = {b2[2], b2[2]};
        #pragma unroll
        for (int ci = 0; ci < 6; ++ci) {
            const float* hb = sh1 + ci * 496 + (u + 4) * 2;   // pos u-2
            f2 H[5];
            #pragma unroll
            for (int k = 0; k < 5; ++k) H[k] = *(const f2*)(hb + 2 * k);
            #pragma unroll
            for (int k = 0; k < 5; ++k) {
                pkfma(a0, H[k], W2[0 * 30 + ci * 5 + k]);
                pkfma(a1, H[k], W2[1 * 30 + ci * 5 + k]);
                pkfma(a2, H[k], W2[2 * 30 + ci * 5 + k]);
            }
        }
        *(f2*)(sh2 + 0 * 488 + (u + 4) * 2) = elu2(a0);
        *(f2*)(sh2 + 1 * 488 + (u + 4) * 2) = elu2(a1);
        *(f2*)(sh2 + 2 * 488 + (u + 4) * 2) = elu2(a2);
    }
    __syncthreads();

    // ---- S4: y, pos v in [-2,T+2), 240 threads; clip(elu(a),0,1)==clamp(a,0,1) ----
    const float B3v = b3[0];
    const float d0 = dw[0], d1 = dw[1], d2 = dw[2], d3 = dw[3], d4 = dw[4];
    const float K = 1.41421356237309515f * (float)(2.0/16384.0) * (float)(2.0/16384.0);
    if (tid < T + 4) {
        const int v = tid - 2;
        f2 a = {B3v, B3v};
        #pragma unroll
        for (int ci = 0; ci < 3; ++ci) {
            const float* hb = sh2 + ci * 488 + (v + 2) * 2;   // pos v-2
            #pragma unroll
            for (int k = 0; k < 5; ++k)
                pkfma(a, *(const f2*)(hb + 2 * k), W3[ci * 5 + k]);
        }
        // xd recomputed from staged x (pos v-2 .. v+2)
        f2 xd = {0.0f, 0.0f};
        const float* xb = sxi + (v + 8) * 2;                  // (v-2+10)*2
        pkfma(xd, *(const f2*)(xb + 0), d0);
        pkfma(xd, *(const f2*)(xb + 2), d1);
        pkfma(xd, *(const f2*)(xb + 4), d2);
        pkfma(xd, *(const f2*)(xb + 6), d3);
        pkfma(xd, *(const f2*)(xb + 8), d4);
        f2 y;
        {
            float c0 = fminf(fmaxf(a.x, 0.0f), 1.0f);
            float c1 = fminf(fmaxf(a.y, 0.0f), 1.0f);
            y.x = (c0 * c0 * K) * fabsf(xd.x) * xd.x;
            y.y = (c1 * c1 * K) * fabsf(xd.y) * xd.y;
        }
        *(f2*)(sy + (v + 2) * 2) = y;                         // aliases dead sh1
    }
    __syncthreads();

    // ---- S5: out = conv5(y,dw), pos s in [0,T), 236 threads ----
    if (tid < T) {
        const int s = tid;
        f2 o = {0.0f, 0.0f};
        const float* yb = sy + s * 2;                         // pos s-2
        pkfma(o, *(const f2*)(yb + 0), d0);
        pkfma(o, *(const f2*)(yb + 2), d1);
        pkfma(o, *(const f2*)(yb + 4), d2);
        pkfma(o, *(const f2*)(yb + 6), d3);
        pkfma(o, *(const f2*)(yb + 8), d4);
        const int g = (tb + s) & (NN - 1);
        o0[g] = o.x;
        o1[g] = o.y;
    }
}

extern "C" void kernel_launch(void* const* d_in, const int* in_sizes, int n_in,
                              void* d_out, int out_size, void* d_ws, size_t ws_size,
                              hipStream_t stream) {
    const float* x  = (const float*)d_in[0];
    const float* dw = (const float*)d_in[1];
    const float* fw = (const float*)d_in[2];
    const float* W1 = (const float*)d_in[3];
    const float* b1 = (const float*)d_in[4];
    const float* W2 = (const float*)d_in[5];
    const float* b2 = (const float*)d_in[6];
    const float* W3 = (const float*)d_in[7];
    const float* b3 = (const float*)d_in[8];
    float* out = (float*)d_out;
    float* cw  = (float*)d_ws;   // 54 floats

    hipLaunchKernelGGL(smag_setup, dim3(1), dim3(64), 0, stream, dw, fw, W1, cw);

    const int B = 1024;
    dim3 grid((B / 2) * TILES);   // 512 row-pairs x 70 tiles = 35840 blocks
    dim3 block(256);
    hipLaunchKernelGGL(smag_bp, grid, block, 0, stream,
                       x, dw, cw, b1, W2, b2, W3, b3, out);
}